// Round 12
// baseline (289.158 us; speedup 1.0000x reference)
//
#include <hip/hip_runtime.h>

typedef __bf16 bf16;
typedef bf16 bf16x2 __attribute__((ext_vector_type(2)));
typedef bf16 bf16x4 __attribute__((ext_vector_type(4)));
typedef bf16 bf16x8 __attribute__((ext_vector_type(8)));
typedef float f32x4 __attribute__((ext_vector_type(4)));
typedef float f32x16 __attribute__((ext_vector_type(16)));
typedef int i32x2 __attribute__((ext_vector_type(2)));
typedef int i32x4 __attribute__((ext_vector_type(4)));

#define SEQ 256
#define DH  32
#define VT_PAD 264   // bf16 row stride 528B = 33*16B
#define KB_PAD 40    // bf16 row stride  80B =  5*16B
#define TRP 36       // tri tile padded cols (floats): 144B row -> bank-spread

// pack two f32 -> one dword of 2 bf16 (v_cvt_pk_bf16_f32)
static __device__ __forceinline__ int pk2(float a, float b) {
    bf16x2 t; t[0] = (bf16)a; t[1] = (bf16)b;
    return __builtin_bit_cast(int, t);
}

// One C-register group G of the 32x32 QK^T output -> exp2 -> two packed dwords
// covering t = 8G+4hi+{0..3}. Tile already holds (tri+mask)*log2e.
template<int G>
static __device__ __forceinline__ i32x2 pgrp(f32x16 cf, f32x4 tg, float& lp) {
    constexpr float K1 = 0.17677669529663687f * 1.44269504088896f; // sm_scale*log2e
    float p0 = __builtin_amdgcn_exp2f(fmaf(cf[4*G+0], K1, tg[0]));
    float p1 = __builtin_amdgcn_exp2f(fmaf(cf[4*G+1], K1, tg[1]));
    float p2 = __builtin_amdgcn_exp2f(fmaf(cf[4*G+2], K1, tg[2]));
    float p3 = __builtin_amdgcn_exp2f(fmaf(cf[4*G+3], K1, tg[3]));
    lp += (p0 + p1) + (p2 + p3);
    i32x2 r; r[0] = pk2(p0, p1); r[1] = pk2(p2, p3);
    return r;
}

// 4 permlane32_swap -> two PV A-frags (t-local 0..15 and 16..31)
static __device__ __forceinline__ void frags(i32x2 a0, i32x2 a1, i32x2 a2, i32x2 a3,
                                             bf16x8& f0, bf16x8& f1) {
    i32x2 s0 = __builtin_amdgcn_permlane32_swap(a0[0], a1[0], false, false);
    i32x2 s1 = __builtin_amdgcn_permlane32_swap(a0[1], a1[1], false, false);
    i32x2 s2 = __builtin_amdgcn_permlane32_swap(a2[0], a3[0], false, false);
    i32x2 s3 = __builtin_amdgcn_permlane32_swap(a2[1], a3[1], false, false);
    i32x4 w0 = {s0[0], s1[0], s0[1], s1[1]};
    i32x4 w1 = {s2[0], s3[0], s2[1], s3[1]};
    f0 = __builtin_bit_cast(bf16x8, w0);
    f1 = __builtin_bit_cast(bf16x8, w1);
}

// wave-private tri tile (64 rows x 32 cols, chunk cc) -> 8 named regs + mask.
// Coalesced: instr i covers rows sbase+i*8..+7, each row a dense 128B segment.
#define LOAD_TRI(cc)                                              \
    sA = *(const f32x4*)(tstage + (cc) * 32 + 0 * 8 * SEQ);       \
    sB = *(const f32x4*)(tstage + (cc) * 32 + 1 * 8 * SEQ);       \
    sC = *(const f32x4*)(tstage + (cc) * 32 + 2 * 8 * SEQ);       \
    sD = *(const f32x4*)(tstage + (cc) * 32 + 3 * 8 * SEQ);       \
    sE = *(const f32x4*)(tstage + (cc) * 32 + 4 * 8 * SEQ);       \
    sF = *(const f32x4*)(tstage + (cc) * 32 + 5 * 8 * SEQ);       \
    sG = *(const f32x4*)(tstage + (cc) * 32 + 6 * 8 * SEQ);       \
    sH = *(const f32x4*)(tstage + (cc) * 32 + 7 * 8 * SEQ);       \
    mq = *(const f32x4*)(mstage + (cc) * 32);

// store tile = tri*log2e + mask*log2e (both biases folded off the hot path)
#define STORE_TRI()                                               \
    {                                                             \
        f32x4 mkl;                                                \
        mkl[0] = mq[0] * LOG2E; mkl[1] = mq[1] * LOG2E;           \
        mkl[2] = mq[2] * LOG2E; mkl[3] = mq[3] * LOG2E;           \
        f32x4 w;                                                  \
        w[0]=fmaf(sA[0],LOG2E,mkl[0]); w[1]=fmaf(sA[1],LOG2E,mkl[1]); \
        w[2]=fmaf(sA[2],LOG2E,mkl[2]); w[3]=fmaf(sA[3],LOG2E,mkl[3]); \
        *(f32x4*)(twr + 0 * 8 * TRP) = w;                         \
        w[0]=fmaf(sB[0],LOG2E,mkl[0]); w[1]=fmaf(sB[1],LOG2E,mkl[1]); \
        w[2]=fmaf(sB[2],LOG2E,mkl[2]); w[3]=fmaf(sB[3],LOG2E,mkl[3]); \
        *(f32x4*)(twr + 1 * 8 * TRP) = w;                         \
        w[0]=fmaf(sC[0],LOG2E,mkl[0]); w[1]=fmaf(sC[1],LOG2E,mkl[1]); \
        w[2]=fmaf(sC[2],LOG2E,mkl[2]); w[3]=fmaf(sC[3],LOG2E,mkl[3]); \
        *(f32x4*)(twr + 2 * 8 * TRP) = w;                         \
        w[0]=fmaf(sD[0],LOG2E,mkl[0]); w[1]=fmaf(sD[1],LOG2E,mkl[1]); \
        w[2]=fmaf(sD[2],LOG2E,mkl[2]); w[3]=fmaf(sD[3],LOG2E,mkl[3]); \
        *(f32x4*)(twr + 3 * 8 * TRP) = w;                         \
        w[0]=fmaf(sE[0],LOG2E,mkl[0]); w[1]=fmaf(sE[1],LOG2E,mkl[1]); \
        w[2]=fmaf(sE[2],LOG2E,mkl[2]); w[3]=fmaf(sE[3],LOG2E,mkl[3]); \
        *(f32x4*)(twr + 4 * 8 * TRP) = w;                         \
        w[0]=fmaf(sF[0],LOG2E,mkl[0]); w[1]=fmaf(sF[1],LOG2E,mkl[1]); \
        w[2]=fmaf(sF[2],LOG2E,mkl[2]); w[3]=fmaf(sF[3],LOG2E,mkl[3]); \
        *(f32x4*)(twr + 5 * 8 * TRP) = w;                         \
        w[0]=fmaf(sG[0],LOG2E,mkl[0]); w[1]=fmaf(sG[1],LOG2E,mkl[1]); \
        w[2]=fmaf(sG[2],LOG2E,mkl[2]); w[3]=fmaf(sG[3],LOG2E,mkl[3]); \
        *(f32x4*)(twr + 6 * 8 * TRP) = w;                         \
        w[0]=fmaf(sH[0],LOG2E,mkl[0]); w[1]=fmaf(sH[1],LOG2E,mkl[1]); \
        w[2]=fmaf(sH[2],LOG2E,mkl[2]); w[3]=fmaf(sH[3],LOG2E,mkl[3]); \
        *(f32x4*)(twr + 7 * 8 * TRP) = w;                         \
    }

// pre-read ALL LDS operands for chunk (cc): tile t/u rows + K/V frags.
// Issued at the BOTTOM of chunk cc-1 (after STORE_TRI deposited chunk cc's
// tile data; same-wave DS ordering makes write->read race-free). Consumed at
// the head of chunk cc -> ~full chunk of latency cover, zero exposed LDS wait.
#define PREREAD(cc)                                               \
    ct0 = *(const f32x4*)(trd + 0);                               \
    ct1 = *(const f32x4*)(trd + 8);                               \
    ct2 = *(const f32x4*)(trd + 16);                              \
    ct3 = *(const f32x4*)(trd + 24);                              \
    cu0 = *(const f32x4*)(trd + 32 * TRP + 0);                    \
    cu1 = *(const f32x4*)(trd + 32 * TRP + 8);                    \
    cu2 = *(const f32x4*)(trd + 32 * TRP + 16);                   \
    cu3 = *(const f32x4*)(trd + 32 * TRP + 24);                   \
    ckf0 = *(const bf16x8*)&Kb[(cc) * 32 + l31][hi * 8];          \
    ckf1 = *(const bf16x8*)&Kb[(cc) * 32 + l31][16 + hi * 8];     \
    cvf0 = *(const bf16x8*)&Vt[l31][(cc) * 32 + hi * 8];          \
    cvf1 = *(const bf16x8*)&Vt[l31][(cc) * 32 + 16 + hi * 8];

// S^T = K*Q^T with 32x32x16 MFMAs (M=t keys, N=s queries).
// C layout: col = s = lane&31, row = t = (reg&3) + 8*(reg>>2) + 4*(lane>>5).
// R12 = R11 + software-pipelined LDS reads (tile/K/V) one chunk ahead + full
// unroll. R11's chunk head exposed 3-4 x ~120cy ds_read latency on the serial
// chain every chunk (reads issued at point of use; compiler can't hoist across
// the STORE_TRI aliasing barrier) -- the one pathology common to ALL ~50us
// variants. Stile-throughput invariant (145-163/us across R2-R11) says TLP/
// ILP/instr-count don't move it; exposed latency is the last untested stall.
// NOTE: min-waves/EU=2: higher values squeeze VGPRs -> scratch spill
// (R1: 456MB, R3: 235MB, R8: 47MB phantom WRITE_SIZE).
__global__ __launch_bounds__(256, 2) void attn_mfma_kernel(
    const float* __restrict__ q,
    const float* __restrict__ k,
    const float* __restrict__ v,
    const float* __restrict__ mask_bias,   // [N][SEQ]
    const float* __restrict__ tri_bias,    // [H][SEQ][SEQ]
    float* __restrict__ out)
{
    __shared__ __align__(16) bf16  Vt[DH][VT_PAD];   // V^T bf16: 16896 B
    __shared__ __align__(16) bf16  Kb[SEQ][KB_PAD];  // K bf16:   20480 B
    __shared__ __align__(16) float Tr[4][64][TRP];   // tri tiles: 36864 B (74.2 KB)

    const int tid  = threadIdx.x;
    const int wave = tid >> 6;
    const int lane = tid & 63;
    const int l31  = lane & 31;
    const int hi   = lane >> 5;

    const int inst = blockIdx.x;       // n*4 + h
    const int n    = inst >> 2;
    const int h    = inst & 3;

    const float* qb = q + (size_t)inst * SEQ * DH;
    const float* kb = k + (size_t)inst * SEQ * DH;
    const float* vb = v + (size_t)inst * SEQ * DH;
    const float* mb = mask_bias + (size_t)n * SEQ;
    const float* tb = tri_bias + (size_t)h * SEQ * SEQ;

    constexpr float LOG2E = 1.44269504088896f;

    const int sbase = wave * 64;       // wave owns 64 queries = 2 stiles of 32

    // coalesced tri staging: lane covers row sbase+(lane>>3)+8i, 16B col (lane&7)
    const float* tstage = tb + (size_t)(sbase + (lane >> 3)) * SEQ + (lane & 7) * 4;
    const float* mstage = mb + (lane & 7) * 4;
    float*       twr    = &Tr[wave][lane >> 3][(lane & 7) * 4];
    const float* trd    = &Tr[wave][l31][hi * 4];   // tile read base (col 8g+4hi)

    f32x4 sA, sB, sC, sD, sE, sF, sG, sH, mq;

    // ---- issue chunk0 tri+mask loads first (in flight across all staging) ----
    LOAD_TRI(0);

    // ---- Q b-frags: qfSD = Q[sbase+S*32+l31][D*16 + hi*8 .. +7] ----
    bf16x8 qf00, qf01, qf10, qf11;
    {
        const float* p0 = qb + (size_t)(sbase + l31) * DH + hi * 8;
        const float* p1 = qb + (size_t)(sbase + 32 + l31) * DH + hi * 8;
        f32x4 a, b;
        bf16x8 f;
        a = ((const f32x4*)p0)[0]; b = ((const f32x4*)p0)[1];
        f[0]=(bf16)a[0]; f[1]=(bf16)a[1]; f[2]=(bf16)a[2]; f[3]=(bf16)a[3];
        f[4]=(bf16)b[0]; f[5]=(bf16)b[1]; f[6]=(bf16)b[2]; f[7]=(bf16)b[3];
        qf00 = f;
        a = ((const f32x4*)(p0 + 16))[0]; b = ((const f32x4*)(p0 + 16))[1];
        f[0]=(bf16)a[0]; f[1]=(bf16)a[1]; f[2]=(bf16)a[2]; f[3]=(bf16)a[3];
        f[4]=(bf16)b[0]; f[5]=(bf16)b[1]; f[6]=(bf16)b[2]; f[7]=(bf16)b[3];
        qf01 = f;
        a = ((const f32x4*)p1)[0]; b = ((const f32x4*)p1)[1];
        f[0]=(bf16)a[0]; f[1]=(bf16)a[1]; f[2]=(bf16)a[2]; f[3]=(bf16)a[3];
        f[4]=(bf16)b[0]; f[5]=(bf16)b[1]; f[6]=(bf16)b[2]; f[7]=(bf16)b[3];
        qf10 = f;
        a = ((const f32x4*)(p1 + 16))[0]; b = ((const f32x4*)(p1 + 16))[1];
        f[0]=(bf16)a[0]; f[1]=(bf16)a[1]; f[2]=(bf16)a[2]; f[3]=(bf16)a[3];
        f[4]=(bf16)b[0]; f[5]=(bf16)b[1]; f[6]=(bf16)b[2]; f[7]=(bf16)b[3];
        qf11 = f;
    }

    // ---- stage V^T (bf16) + K (bf16) into LDS (coalesced) ----
    #pragma unroll
    for (int i = 0; i < 8; ++i) {
        int idx = i * 256 + tid;       // float4 index: t = idx>>3, d-group = idx&7
        int t   = idx >> 3;
        int d4  = (idx & 7) * 4;
        f32x4 tv = ((const f32x4*)vb)[idx];
        Vt[d4 + 0][t] = (bf16)tv[0];
        Vt[d4 + 1][t] = (bf16)tv[1];
        Vt[d4 + 2][t] = (bf16)tv[2];
        Vt[d4 + 3][t] = (bf16)tv[3];
        f32x4 tk = ((const f32x4*)kb)[idx];
        bf16x4 kk;
        kk[0]=(bf16)tk[0]; kk[1]=(bf16)tk[1]; kk[2]=(bf16)tk[2]; kk[3]=(bf16)tk[3];
        *(bf16x4*)&Kb[t][d4] = kk;
    }

    // tile <- chunk0 (biases folded); then chunk1 global loads
    STORE_TRI();
    LOAD_TRI(1);

    __syncthreads();                   // Vt/Kb visible to all waves

    // ---- pre-read chunk0 LDS operands (tile after STORE_TRI: in-order DS) ----
    f32x4 ct0, ct1, ct2, ct3, cu0, cu1, cu2, cu3;
    bf16x8 ckf0, ckf1, cvf0, cvf1;
    PREREAD(0);

    f32x16 oacc0 = {}, oacc1 = {};
    float lp0a = 0.f, lp0b = 0.f, lp1a = 0.f, lp1b = 0.f;
    const f32x16 z16 = {};

    // ---- main loop: 8 chunks of 32 keys, fully unrolled, LDS zero-wait heads ----
    #pragma unroll
    for (int c = 0; c < 8; ++c) {
        // ============ stile 0 (all operands pre-read last chunk) ============
        f32x16 cf = __builtin_amdgcn_mfma_f32_32x32x16_bf16(ckf0, qf00, z16, 0, 0, 0);
        cf = __builtin_amdgcn_mfma_f32_32x32x16_bf16(ckf1, qf01, cf, 0, 0, 0);

        i32x2 a0 = pgrp<0>(cf, ct0, lp0a);
        i32x2 a1 = pgrp<1>(cf, ct1, lp0b);
        i32x2 a2 = pgrp<2>(cf, ct2, lp0a);
        i32x2 a3 = pgrp<3>(cf, ct3, lp0b);
        bf16x8 pa0, pa1;
        frags(a0, a1, a2, a3, pa0, pa1);

        oacc0 = __builtin_amdgcn_mfma_f32_32x32x16_bf16(pa0, cvf0, oacc0, 0, 0, 0);
        oacc0 = __builtin_amdgcn_mfma_f32_32x32x16_bf16(pa1, cvf1, oacc0, 0, 0, 0);

        // tile <- chunk c+1 (regs loaded last chunk); start chunk c+2 globals
        if (c < 7) { STORE_TRI(); }
        if (c < 6) { LOAD_TRI(c + 2); }

        // ============ stile 1 ============
        cf = __builtin_amdgcn_mfma_f32_32x32x16_bf16(ckf0, qf10, z16, 0, 0, 0);
        cf = __builtin_amdgcn_mfma_f32_32x32x16_bf16(ckf1, qf11, cf, 0, 0, 0);

        a0 = pgrp<0>(cf, cu0, lp1a);
        a1 = pgrp<1>(cf, cu1, lp1b);
        a2 = pgrp<2>(cf, cu2, lp1a);
        a3 = pgrp<3>(cf, cu3, lp1b);
        bf16x8 pb0, pb1;
        frags(a0, a1, a2, a3, pb0, pb1);

        oacc1 = __builtin_amdgcn_mfma_f32_32x32x16_bf16(pb0, cvf0, oacc1, 0, 0, 0);
        oacc1 = __builtin_amdgcn_mfma_f32_32x32x16_bf16(pb1, cvf1, oacc1, 0, 0, 0);

        // ---- pre-read chunk c+1 operands (tile written above; in-order DS;
        // stile-1 compute above provides the issue slack) ----
        if (c < 7) { PREREAD(c + 1); }
    }

    // ---- softmax denominators: hi-half reduce, then normalize + store ----
    float lp0 = lp0a + lp0b;
    float lp1 = lp1a + lp1b;
    lp0 += __shfl_xor(lp0, 32);
    lp1 += __shfl_xor(lp1, 32);
    const float li0 = 1.0f / lp0;      // valid for s = sbase + l31
    const float li1 = 1.0f / lp1;      // valid for s = sbase + 32 + l31

    float* ob = out + (size_t)inst * SEQ * DH;
    #pragma unroll
    for (int r = 0; r < 16; ++r) {
        const int srow = (r & 3) + 8 * (r >> 2) + 4 * hi;
        float i0 = __shfl(li0, srow);  // 1/l for row srow lives in lane srow
        float i1 = __shfl(li1, srow);
        ob[(size_t)(sbase + srow) * DH + l31]      = oacc0[r] * i0;
        ob[(size_t)(sbase + 32 + srow) * DH + l31] = oacc1[r] * i1;
    }
}

extern "C" void kernel_launch(void* const* d_in, const int* in_sizes, int n_in,
                              void* d_out, int out_size, void* d_ws, size_t ws_size,
                              hipStream_t stream) {
    const float* q    = (const float*)d_in[0];
    const float* k    = (const float*)d_in[1];
    const float* v    = (const float*)d_in[2];
    const float* mask = (const float*)d_in[3];
    const float* tri  = (const float*)d_in[4];
    float* out = (float*)d_out;

    attn_mfma_kernel<<<dim3(256 * 4), dim3(256), 0, stream>>>(q, k, v, mask, tri, out);
}